// Round 2
// baseline (2185.860 us; speedup 1.0000x reference)
//
#include <hip/hip_runtime.h>

#define C_    384
#define NH_   12
#define DH_   32
#define HPX   128
#define WPX   128
#define NWIN_ 4096
#define TOK_  262144   // NWIN_ * 64

typedef __attribute__((ext_vector_type(8))) short short8;
typedef __attribute__((ext_vector_type(4))) float f32x4;

__device__ __forceinline__ unsigned short f2bf(float f) {
  unsigned u = __builtin_bit_cast(unsigned, f);
  u = (u + 0x7fffu + ((u >> 16) & 1u)) >> 16;   // RNE
  return (unsigned short)u;
}

// ------------------------------------------------------------------
// prep: cast in_proj_w to bf16; fuse out_proj+proj into Wf, bf
// ------------------------------------------------------------------
__global__ __launch_bounds__(256) void prep_kernel(
    const float* __restrict__ in_w, const float* __restrict__ op_w,
    const float* __restrict__ op_b, const float* __restrict__ p_w,
    const float* __restrict__ p_b, unsigned short* __restrict__ wqkv,
    unsigned short* __restrict__ wf, float* __restrict__ bfv)
{
  int tid = blockIdx.x * blockDim.x + threadIdx.x;
  int stride = gridDim.x * blockDim.x;
  for (int i = tid; i < 3 * C_ * C_; i += stride) wqkv[i] = f2bf(in_w[i]);
  for (int i = tid; i < C_ * C_; i += stride) {
    int r = i / C_, c = i % C_;
    float acc = 0.f;
    for (int k = 0; k < C_; k++) acc += p_w[r * C_ + k] * op_w[k * C_ + c];
    wf[i] = f2bf(acc);
  }
  for (int i = tid; i < C_; i += stride) {
    float acc = p_b[i];
    for (int k = 0; k < C_; k++) acc += p_w[i * C_ + k] * op_b[k];
    bfv[i] = acc;
  }
}

// ------------------------------------------------------------------
// fused window-partition + LayerNorm + QKV + attention -> o1 (bf16)
// one block per window, 256 threads (4 waves)
// LDS: xn[64][384] bf16 swizzled (49152) | Qb[64][32] (4096) |
//      Kb[64][32] (4096) | VTb[32][64] (4096); Pb[64][64] overlays Qb+Kb
// ------------------------------------------------------------------
__global__ __launch_bounds__(256) void fused_attn(
    const float* __restrict__ x, const float* __restrict__ gamma,
    const float* __restrict__ beta, const unsigned short* __restrict__ wqkv,
    const float* __restrict__ bqkv, unsigned short* __restrict__ o1)
{
  __shared__ char smem[61440];
  char* xnb = smem;            // [64][384] bf16, byte ^= (tok&7)<<4
  char* Qb  = smem + 49152;    // [64][32] bf16, byte ^= (tok&7)<<4
  char* Kb  = smem + 53248;    // [64][32]
  char* VTb = smem + 57344;    // [32][64] (d-major), byte ^= (d&7)<<4
  char* Pb  = smem + 49152;    // [64][64] overlay (Qb+Kb dead)
  float* red   = (float*)(smem + 49152);         // phase-1 partials (overlay)
  float* stats = (float*)(smem + 49152 + 2048);  // mu, rsig per token

  // XCD-aware swizzle: 4096 % 8 == 0, bijective. Same-XCD blocks become
  // spatially adjacent windows -> shared 64B x-lines + wqkv L2 reuse.
  const int win = (blockIdx.x & 7) * (NWIN_ / 8) + (blockIdx.x >> 3);
  const int bt = win >> 8, wh = (win >> 4) & 15, ww = win & 15;
  const int tid = threadIdx.x;
  const int w = tid >> 6, l = tid & 63;
  const int l15 = l & 15, sub = l >> 4;

  const float* xb = x + ((size_t)bt * C_ * HPX + (size_t)wh * 8) * WPX + ww * 8;
  const int i0 = l >> 3, j0 = l & 7;

  // ---- phase 1: LN stats (lane = token, wave strides channels) ----
  float sm = 0.f, sq = 0.f;
  for (int c = w; c < C_; c += 4) {
    float v = xb[(size_t)c * (HPX * WPX) + i0 * WPX + j0];
    sm += v; sq += v * v;
  }
  red[(w * 64 + l) * 2] = sm;
  red[(w * 64 + l) * 2 + 1] = sq;
  __syncthreads();
  if (tid < 64) {
    float a0 = 0.f, a1 = 0.f;
    for (int p = 0; p < 4; p++) { a0 += red[(p * 64 + tid) * 2]; a1 += red[(p * 64 + tid) * 2 + 1]; }
    float mu = a0 * (1.f / C_);
    float var = a1 * (1.f / C_) - mu * mu;
    stats[tid * 2] = mu;
    stats[tid * 2 + 1] = rsqrtf(var + 1e-5f);
  }
  __syncthreads();
  const float mu = stats[l * 2], rsg = stats[l * 2 + 1];

  // ---- phase 2: normalize, cast bf16, store swizzled xn ----
  for (int c = w; c < C_; c += 4) {
    float v = xb[(size_t)c * (HPX * WPX) + i0 * WPX + j0];
    float xv = (v - mu) * rsg * gamma[c] + beta[c];
    unsigned byte = (unsigned)(l * 768 + c * 2) ^ (unsigned)((l & 7) << 4);
    *(unsigned short*)(xnb + byte) = f2bf(xv);
  }
  __syncthreads();

  const int mw = w >> 1, nw = w & 1;
  const float scale = 0.1767766952966369f;  // 1/sqrt(32)
  const f32x4 zf = {0.f, 0.f, 0.f, 0.f};

  for (int h = 0; h < NH_; h++) {
    // ---- QKV-gen: wave (mw,nw): rows 32*mw..+31, n-tiles 3*nw..+2 ----
    int wr[3];
    #pragma unroll
    for (int jj = 0; jj < 3; jj++) {
      int j = 3 * nw + jj;
      wr[jj] = (j >> 1) * C_ + h * DH_ + (j & 1) * 16;
    }
    f32x4 acc[2][3];
    #pragma unroll
    for (int r = 0; r < 2; r++)
      #pragma unroll
      for (int jj = 0; jj < 3; jj++) acc[r][jj] = zf;

    for (int kc = 0; kc < 12; kc++) {
      short8 a[2];
      #pragma unroll
      for (int r = 0; r < 2; r++) {
        int tok = 32 * mw + 16 * r + l15;
        unsigned byte = (unsigned)(tok * 768 + kc * 64 + (sub << 4)) ^ (unsigned)((tok & 7) << 4);
        a[r] = *(const short8*)(xnb + byte);
      }
      #pragma unroll
      for (int jj = 0; jj < 3; jj++) {
        short8 b = *(const short8*)(wqkv + ((size_t)(wr[jj] + l15) * C_ + kc * 32 + (sub << 3)));
        acc[0][jj] = __builtin_amdgcn_mfma_f32_16x16x32_bf16(a[0], b, acc[0][jj], 0, 0, 0);
        acc[1][jj] = __builtin_amdgcn_mfma_f32_16x16x32_bf16(a[1], b, acc[1][jj], 0, 0, 0);
      }
    }
    __syncthreads();   // prior PV reads of Pb/VTb complete

    // ---- write Q (scaled), K, V^T to LDS with bias ----
    #pragma unroll
    for (int jj = 0; jj < 3; jj++) {
      int j = 3 * nw + jj;
      int typ = j >> 1;
      int dloc = (j & 1) * 16 + l15;
      float bias = bqkv[wr[jj] + l15];
      #pragma unroll
      for (int r = 0; r < 2; r++) {
        #pragma unroll
        for (int rr = 0; rr < 4; rr++) {
          int tok = 32 * mw + 16 * r + (sub << 2) + rr;
          float v = acc[r][jj][rr] + bias;
          if (typ == 0) {
            v *= scale;
            unsigned byte = (unsigned)(tok * 64 + dloc * 2) ^ (unsigned)((tok & 7) << 4);
            *(unsigned short*)(Qb + byte) = f2bf(v);
          } else if (typ == 1) {
            unsigned byte = (unsigned)(tok * 64 + dloc * 2) ^ (unsigned)((tok & 7) << 4);
            *(unsigned short*)(Kb + byte) = f2bf(v);
          } else {
            unsigned byte = (unsigned)(dloc * 128 + tok * 2) ^ (unsigned)((dloc & 7) << 4);
            *(unsigned short*)(VTb + byte) = f2bf(v);
          }
        }
      }
    }
    __syncthreads();

    // ---- S = Q K^T : wave w owns q-rows 16w..16w+15 ----
    short8 qa;
    {
      int tok = 16 * w + l15;
      unsigned byte = (unsigned)(tok * 64 + (sub << 4)) ^ (unsigned)((tok & 7) << 4);
      qa = *(const short8*)(Qb + byte);
    }
    f32x4 sacc[4];
    #pragma unroll
    for (int ct = 0; ct < 4; ct++) {
      int kt = ct * 16 + l15;
      unsigned byte = (unsigned)(kt * 64 + (sub << 4)) ^ (unsigned)((kt & 7) << 4);
      short8 kb = *(const short8*)(Kb + byte);
      sacc[ct] = __builtin_amdgcn_mfma_f32_16x16x32_bf16(qa, kb, zf, 0, 0, 0);
    }
    // ---- softmax (rows live in 16-lane groups) ----
    float inv[4];
    #pragma unroll
    for (int rr = 0; rr < 4; rr++) {
      float m = fmaxf(fmaxf(sacc[0][rr], sacc[1][rr]), fmaxf(sacc[2][rr], sacc[3][rr]));
      m = fmaxf(m, __shfl_xor(m, 1));
      m = fmaxf(m, __shfl_xor(m, 2));
      m = fmaxf(m, __shfl_xor(m, 4));
      m = fmaxf(m, __shfl_xor(m, 8));
      float s = 0.f;
      #pragma unroll
      for (int ct = 0; ct < 4; ct++) {
        float p = __expf(sacc[ct][rr] - m);
        sacc[ct][rr] = p;
        s += p;
      }
      s += __shfl_xor(s, 1); s += __shfl_xor(s, 2);
      s += __shfl_xor(s, 4); s += __shfl_xor(s, 8);
      inv[rr] = 1.0f / s;
    }
    __syncthreads();   // all waves done reading Qb/Kb before P overlays them
    #pragma unroll
    for (int ct = 0; ct < 4; ct++)
      #pragma unroll
      for (int rr = 0; rr < 4; rr++) {
        int q = 16 * w + (sub << 2) + rr;
        int kk = ct * 16 + l15;
        unsigned byte = (unsigned)(q * 128 + kk * 2) ^ (unsigned)((q & 7) << 4);
        *(unsigned short*)(Pb + byte) = f2bf(sacc[ct][rr]);
      }
    __syncthreads();

    // ---- O = P V ----
    f32x4 oacc[2] = {zf, zf};
    #pragma unroll
    for (int kc = 0; kc < 2; kc++) {
      int q = 16 * w + l15;
      unsigned pb = (unsigned)(q * 128 + kc * 64 + (sub << 4)) ^ (unsigned)((q & 7) << 4);
      short8 pa = *(const short8*)(Pb + pb);
      #pragma unroll
      for (int dt = 0; dt < 2; dt++) {
        int d = dt * 16 + l15;
        unsigned vb = (unsigned)(d * 128 + kc * 64 + (sub << 4)) ^ (unsigned)((d & 7) << 4);
        short8 vv = *(const short8*)(VTb + vb);
        oacc[dt] = __builtin_amdgcn_mfma_f32_16x16x32_bf16(pa, vv, oacc[dt], 0, 0, 0);
      }
    }
    #pragma unroll
    for (int dt = 0; dt < 2; dt++)
      #pragma unroll
      for (int rr = 0; rr < 4; rr++) {
        int q = 16 * w + (sub << 2) + rr;
        int col = h * DH_ + dt * 16 + l15;
        o1[(size_t)(win * 64 + q) * C_ + col] = f2bf(oacc[dt][rr] * inv[rr]);
      }
  }
}

// ------------------------------------------------------------------
// final: out = o1 @ Wf^T + bf, written back in (B,T,C,H,W) layout
// 128x128 tile, BK=64, 256 threads (4 waves, 2x2), swizzled LDS
// ------------------------------------------------------------------
__global__ __launch_bounds__(256) void final_gemm(
    const unsigned short* __restrict__ o1, const unsigned short* __restrict__ wf,
    const float* __restrict__ bfv, float* __restrict__ out)
{
  __shared__ char smem[32768];
  char* As = smem;            // [128][64] bf16, byte ^= (row&7)<<4
  char* Bs = smem + 16384;

  const int blk = blockIdx.x;
  const int nt = blk % 3, mt = blk / 3;
  const int mbase = mt * 128, nbase = nt * 128;
  const int tid = threadIdx.x;
  const int w = tid >> 6, l = tid & 63;
  const int l15 = l & 15, sub = l >> 4;
  const int wm = w >> 1, wn = w & 1;
  const f32x4 zf = {0.f, 0.f, 0.f, 0.f};

  f32x4 acc[4][4];
  #pragma unroll
  for (int r = 0; r < 4; r++)
    #pragma unroll
    for (int c = 0; c < 4; c++) acc[r][c] = zf;

  for (int kb = 0; kb < C_; kb += 64) {
    __syncthreads();
    #pragma unroll
    for (int it = 0; it < 4; it++) {
      int row = it * 32 + (tid >> 3);
      int seg = tid & 7;
      unsigned byte = (unsigned)(row * 128 + seg * 16) ^ (unsigned)((row & 7) << 4);
      short8 va = *(const short8*)(o1 + (size_t)(mbase + row) * C_ + kb + seg * 8);
      *(short8*)(As + byte) = va;
      short8 vb = *(const short8*)(wf + (size_t)(nbase + row) * C_ + kb + seg * 8);
      *(short8*)(Bs + byte) = vb;
    }
    __syncthreads();
    #pragma unroll
    for (int kc = 0; kc < 2; kc++) {
      short8 a[4], b[4];
      #pragma unroll
      for (int r = 0; r < 4; r++) {
        int row = wm * 64 + r * 16 + l15;
        unsigned byte = (unsigned)(row * 128 + kc * 64 + (sub << 4)) ^ (unsigned)((row & 7) << 4);
        a[r] = *(const short8*)(As + byte);
      }
      #pragma unroll
      for (int c = 0; c < 4; c++) {
        int row = wn * 64 + c * 16 + l15;
        unsigned byte = (unsigned)(row * 128 + kc * 64 + (sub << 4)) ^ (unsigned)((row & 7) << 4);
        b[c] = *(const short8*)(Bs + byte);
      }
      #pragma unroll
      for (int r = 0; r < 4; r++)
        #pragma unroll
        for (int c = 0; c < 4; c++)
          acc[r][c] = __builtin_amdgcn_mfma_f32_16x16x32_bf16(a[r], b[c], acc[r][c], 0, 0, 0);
    }
  }

  // epilogue: add bias, merge windows back to (B,T,C,H,W)
  #pragma unroll
  for (int r = 0; r < 4; r++) {
    int t0 = mbase + wm * 64 + r * 16 + (sub << 2);   // 4 consecutive tokens
    int win = t0 >> 6, s0 = t0 & 63;
    int bt = win >> 8, wh = (win >> 4) & 15, ww = win & 15;
    int ii = s0 >> 3, jj = s0 & 7;                    // jj in {0,4}
    #pragma unroll
    for (int c4 = 0; c4 < 4; c4++) {
      int c = nbase + wn * 64 + c4 * 16 + l15;
      float bias = bfv[c];
      f32x4 v;
      v[0] = acc[r][c4][0] + bias;
      v[1] = acc[r][c4][1] + bias;
      v[2] = acc[r][c4][2] + bias;
      v[3] = acc[r][c4][3] + bias;
      size_t off = (((size_t)bt * C_ + c) * HPX + wh * 8 + ii) * WPX + ww * 8 + jj;
      *(f32x4*)(out + off) = v;
    }
  }
}

// ------------------------------------------------------------------
extern "C" void kernel_launch(void* const* d_in, const int* in_sizes, int n_in,
                              void* d_out, int out_size, void* d_ws, size_t ws_size,
                              hipStream_t stream)
{
  (void)in_sizes; (void)n_in; (void)out_size; (void)ws_size;
  const float* x     = (const float*)d_in[0];
  const float* gamma = (const float*)d_in[1];
  const float* beta  = (const float*)d_in[2];
  const float* in_w  = (const float*)d_in[3];
  const float* in_b  = (const float*)d_in[4];
  const float* op_w  = (const float*)d_in[5];
  const float* op_b  = (const float*)d_in[6];
  const float* p_w   = (const float*)d_in[7];
  const float* p_b   = (const float*)d_in[8];
  float* out = (float*)d_out;
  char* ws = (char*)d_ws;

  const size_t o1_bytes = (size_t)TOK_ * C_ * 2;          // 201326592
  unsigned short* o1   = (unsigned short*)ws;
  unsigned short* wqkv = (unsigned short*)(ws + o1_bytes);                 // 884736 B
  unsigned short* wf   = (unsigned short*)(ws + o1_bytes + 884736);        // 294912 B
  float*          bfv  = (float*)(ws + o1_bytes + 884736 + 294912);        // 1536 B

  prep_kernel<<<1024, 256, 0, stream>>>(in_w, op_w, op_b, p_w, p_b, wqkv, wf, bfv);
  fused_attn<<<NWIN_, 256, 0, stream>>>(x, gamma, beta, wqkv, in_b, o1);
  final_gemm<<<2048 * 3, 256, 0, stream>>>(o1, wf, bfv, out);
}

// Round 6
// 1882.752 us; speedup vs baseline: 1.1610x; 1.1610x over previous
//
#include <hip/hip_runtime.h>

#define C_    384
#define NH_   12
#define DH_   32
#define HPX   128
#define WPX   128
#define NWIN_ 4096
#define TOK_  262144   // NWIN_ * 64

typedef __attribute__((ext_vector_type(8))) short short8;
typedef __attribute__((ext_vector_type(4))) float f32x4;

__device__ __forceinline__ unsigned short f2bf(float f) {
  unsigned u = __builtin_bit_cast(unsigned, f);
  u = (u + 0x7fffu + ((u >> 16) & 1u)) >> 16;   // RNE
  return (unsigned short)u;
}

// ------------------------------------------------------------------
// prep: cast in_proj_w to bf16; fuse out_proj+proj into Wf, bf
// ------------------------------------------------------------------
__global__ __launch_bounds__(256) void prep_kernel(
    const float* __restrict__ in_w, const float* __restrict__ op_w,
    const float* __restrict__ op_b, const float* __restrict__ p_w,
    const float* __restrict__ p_b, unsigned short* __restrict__ wqkv,
    unsigned short* __restrict__ wf, float* __restrict__ bfv)
{
  int tid = blockIdx.x * blockDim.x + threadIdx.x;
  int stride = gridDim.x * blockDim.x;
  for (int i = tid; i < 3 * C_ * C_; i += stride) wqkv[i] = f2bf(in_w[i]);
  for (int i = tid; i < C_ * C_; i += stride) {
    int r = i / C_, c = i % C_;
    float acc = 0.f;
    for (int k = 0; k < C_; k++) acc += p_w[r * C_ + k] * op_w[k * C_ + c];
    wf[i] = f2bf(acc);
  }
  for (int i = tid; i < C_; i += stride) {
    float acc = p_b[i];
    for (int k = 0; k < C_; k++) acc += p_w[i * C_ + k] * op_b[k];
    bfv[i] = acc;
  }
}

// ------------------------------------------------------------------
// ln_win: window-partition + LayerNorm -> xn (token-major bf16, coalesced)
// one block per window, 256 threads. LDS transpose staging.
// ------------------------------------------------------------------
__global__ __launch_bounds__(256) void ln_win(
    const float* __restrict__ x, const float* __restrict__ gamma,
    const float* __restrict__ beta, unsigned short* __restrict__ xn)
{
  __shared__ char smem[51712];
  char* xnb = smem;                              // [64][384] bf16, ^((tok&7)<<4)
  float* red   = (float*)(smem + 49152);         // 2048 B
  float* stats = (float*)(smem + 49152 + 2048);  // 512 B

  const int win = (blockIdx.x & 7) * (NWIN_ / 8) + (blockIdx.x >> 3);
  const int bt = win >> 8, wh = (win >> 4) & 15, ww = win & 15;
  const int tid = threadIdx.x;
  const int w = tid >> 6, l = tid & 63;
  const float* xb = x + ((size_t)bt * C_ * HPX + (size_t)wh * 8) * WPX + ww * 8;
  const int px = (l >> 3) * WPX + (l & 7);

  // phase 1: LN stats (lane = token, wave strides channel-pairs)
  float sm = 0.f, sq = 0.f;
  for (int cp = w; cp < 192; cp += 4) {
    int c = cp * 2;
    float v0 = xb[(size_t)c * (HPX * WPX) + px];
    float v1 = xb[(size_t)(c + 1) * (HPX * WPX) + px];
    sm += v0 + v1; sq += v0 * v0 + v1 * v1;
  }
  red[(w * 64 + l) * 2] = sm;
  red[(w * 64 + l) * 2 + 1] = sq;
  __syncthreads();
  if (tid < 64) {
    float a0 = 0.f, a1 = 0.f;
    for (int p = 0; p < 4; p++) { a0 += red[(p * 64 + tid) * 2]; a1 += red[(p * 64 + tid) * 2 + 1]; }
    float mu = a0 * (1.f / C_);
    float var = a1 * (1.f / C_) - mu * mu;
    stats[tid * 2] = mu;
    stats[tid * 2 + 1] = rsqrtf(var + 1e-5f);
  }
  __syncthreads();
  const float mu = stats[l * 2], rsg = stats[l * 2 + 1];

  // phase 2: normalize channel pairs, pack u32, swizzled LDS write
  for (int cp = w; cp < 192; cp += 4) {
    int c = cp * 2;
    float v0 = xb[(size_t)c * (HPX * WPX) + px];
    float v1 = xb[(size_t)(c + 1) * (HPX * WPX) + px];
    float y0 = (v0 - mu) * rsg * gamma[c] + beta[c];
    float y1 = (v1 - mu) * rsg * gamma[c + 1] + beta[c + 1];
    unsigned pk = (unsigned)f2bf(y0) | ((unsigned)f2bf(y1) << 16);
    unsigned byte = (unsigned)(l * 768 + c * 2) ^ (unsigned)((l & 7) << 4);
    *(unsigned*)(xnb + byte) = pk;
  }
  __syncthreads();

  // phase 3: vectorized LDS -> global (token-major rows, coalesced)
  unsigned short* xg = xn + (size_t)win * (64 * C_);
  #pragma unroll
  for (int i = 0; i < 12; i++) {
    unsigned g = (unsigned)(i * 4096 + tid * 16);
    unsigned row = g / 768;
    unsigned byte = g ^ ((row & 7) << 4);
    short8 v = *(const short8*)(xnb + byte);
    *(short8*)(xg + (g >> 1)) = v;
  }
}

// ------------------------------------------------------------------
// qkv_gemm: qkv = xn @ wqkv^T + bias (Q scaled). 128x128 tile, BK=64.
// N = 1152: nt 0-2 -> Q (tok,384), 3-5 -> K (tok,384), 6-8 -> V^T (win,384,64)
// ------------------------------------------------------------------
__global__ __launch_bounds__(256) void qkv_gemm(
    const unsigned short* __restrict__ xn, const unsigned short* __restrict__ wqkv,
    const float* __restrict__ bqkv, unsigned short* __restrict__ qs,
    unsigned short* __restrict__ ksp, unsigned short* __restrict__ vt)
{
  __shared__ char smem[32768];
  char* As = smem;            // [128][64] bf16, byte ^= (row&7)<<4
  char* Bs = smem + 16384;

  const int blk = blockIdx.x;
  const int nt = blk % 9, mt = blk / 9;
  const int mbase = mt * 128, nbase = nt * 128;
  const int tid = threadIdx.x;
  const int w = tid >> 6, l = tid & 63;
  const int l15 = l & 15, sub = l >> 4;
  const int wm = w >> 1, wn = w & 1;
  const f32x4 zf = {0.f, 0.f, 0.f, 0.f};
  const float scale = 0.1767766952966369f;  // 1/sqrt(32)

  f32x4 acc[4][4];
  #pragma unroll
  for (int r = 0; r < 4; r++)
    #pragma unroll
    for (int c = 0; c < 4; c++) acc[r][c] = zf;

  for (int kb = 0; kb < C_; kb += 64) {
    __syncthreads();
    #pragma unroll
    for (int it = 0; it < 4; it++) {
      int row = it * 32 + (tid >> 3);
      int seg = tid & 7;
      unsigned byte = (unsigned)(row * 128 + seg * 16) ^ (unsigned)((row & 7) << 4);
      short8 va = *(const short8*)(xn + (size_t)(mbase + row) * C_ + kb + seg * 8);
      *(short8*)(As + byte) = va;
      short8 vb = *(const short8*)(wqkv + (size_t)(nbase + row) * C_ + kb + seg * 8);
      *(short8*)(Bs + byte) = vb;
    }
    __syncthreads();
    #pragma unroll
    for (int kc = 0; kc < 2; kc++) {
      short8 a[4], b[4];
      #pragma unroll
      for (int r = 0; r < 4; r++) {
        int row = wm * 64 + r * 16 + l15;
        unsigned byte = (unsigned)(row * 128 + kc * 64 + (sub << 4)) ^ (unsigned)((row & 7) << 4);
        a[r] = *(const short8*)(As + byte);
      }
      #pragma unroll
      for (int c = 0; c < 4; c++) {
        int row = wn * 64 + c * 16 + l15;
        unsigned byte = (unsigned)(row * 128 + kc * 64 + (sub << 4)) ^ (unsigned)((row & 7) << 4);
        b[c] = *(const short8*)(Bs + byte);
      }
      #pragma unroll
      for (int r = 0; r < 4; r++)
        #pragma unroll
        for (int c = 0; c < 4; c++)
          acc[r][c] = __builtin_amdgcn_mfma_f32_16x16x32_bf16(a[r], b[c], acc[r][c], 0, 0, 0);
    }
  }

  const int typ = nt / 3;
  #pragma unroll
  for (int r = 0; r < 4; r++) {
    int t0 = mbase + wm * 64 + r * 16 + (sub << 2);
    #pragma unroll
    for (int c4 = 0; c4 < 4; c4++) {
      int dg = nbase + wn * 64 + c4 * 16 + l15;
      float bias = bqkv[dg];
      if (typ == 0) {
        #pragma unroll
        for (int reg = 0; reg < 4; reg++)
          qs[(size_t)(t0 + reg) * C_ + dg] = f2bf((acc[r][c4][reg] + bias) * scale);
      } else if (typ == 1) {
        #pragma unroll
        for (int reg = 0; reg < 4; reg++)
          ksp[(size_t)(t0 + reg) * C_ + (dg - C_)] = f2bf(acc[r][c4][reg] + bias);
      } else {
        int vd = dg - 2 * C_;
        int win_l = t0 >> 6, s0 = t0 & 63;
        unsigned short b0 = f2bf(acc[r][c4][0] + bias);
        unsigned short b1 = f2bf(acc[r][c4][1] + bias);
        unsigned short b2 = f2bf(acc[r][c4][2] + bias);
        unsigned short b3 = f2bf(acc[r][c4][3] + bias);
        unsigned lo = (unsigned)b0 | ((unsigned)b1 << 16);
        unsigned hi = (unsigned)b2 | ((unsigned)b3 << 16);
        unsigned* p = (unsigned*)(vt + ((size_t)win_l * C_ + vd) * 64 + s0);
        p[0] = lo; p[1] = hi;
      }
    }
  }
}

// ------------------------------------------------------------------
// attn_win: barrier-free per-window attention. 4 waves; wave w does heads
// {w, w+4, w+8}. Per-wave 8KB P buffer in LDS. Q/K/V read from global (L2).
// ------------------------------------------------------------------
__global__ __launch_bounds__(256, 4) void attn_win(
    const unsigned short* __restrict__ qs, const unsigned short* __restrict__ ksp,
    const unsigned short* __restrict__ vt, unsigned short* __restrict__ o1)
{
  __shared__ char Pall[32768];
  const int win_l = blockIdx.x;
  const int tid = threadIdx.x;
  const int w = tid >> 6, l = tid & 63;
  const int l15 = l & 15, sub = l >> 4;
  char* Pb = Pall + w * 8192;   // [64 q][64 k] u16, byte ^= (q&7)<<4
  const unsigned short* qw = qs + (size_t)win_l * 64 * C_;
  const unsigned short* kw = ksp + (size_t)win_l * 64 * C_;
  const unsigned short* vw = vt + (size_t)win_l * C_ * 64;
  unsigned short* ow = o1 + (size_t)win_l * 64 * C_;
  const f32x4 zf = {0.f, 0.f, 0.f, 0.f};

  for (int hh = 0; hh < 3; hh++) {
    const int h = w + hh * 4;
    // K fragments for all 4 col-tiles (reused by both q-halves)
    short8 kf[4];
    #pragma unroll
    for (int ct = 0; ct < 4; ct++)
      kf[ct] = *(const short8*)(kw + (size_t)(ct * 16 + l15) * C_ + h * DH_ + sub * 8);

    #pragma unroll
    for (int hf = 0; hf < 2; hf++) {
      // S = Q K^T for q-rows [hf*32, hf*32+32)
      f32x4 sc[2][4];
      #pragma unroll
      for (int rt2 = 0; rt2 < 2; rt2++) {
        int rt = hf * 2 + rt2;
        short8 qf = *(const short8*)(qw + (size_t)(rt * 16 + l15) * C_ + h * DH_ + sub * 8);
        #pragma unroll
        for (int ct = 0; ct < 4; ct++)
          sc[rt2][ct] = __builtin_amdgcn_mfma_f32_16x16x32_bf16(qf, kf[ct], zf, 0, 0, 0);
      }
      // softmax (row q = rt*16 + sub*4 + reg; k over ct & l15 group)
      float inv[2][4];
      #pragma unroll
      for (int rt2 = 0; rt2 < 2; rt2++) {
        #pragma unroll
        for (int reg = 0; reg < 4; reg++) {
          float m = fmaxf(fmaxf(sc[rt2][0][reg], sc[rt2][1][reg]),
                          fmaxf(sc[rt2][2][reg], sc[rt2][3][reg]));
          m = fmaxf(m, __shfl_xor(m, 1));
          m = fmaxf(m, __shfl_xor(m, 2));
          m = fmaxf(m, __shfl_xor(m, 4));
          m = fmaxf(m, __shfl_xor(m, 8));
          float s = 0.f;
          #pragma unroll
          for (int ct = 0; ct < 4; ct++) {
            float p = __expf(sc[rt2][ct][reg] - m);
            sc[rt2][ct][reg] = p;
            s += p;
          }
          s += __shfl_xor(s, 1); s += __shfl_xor(s, 2);
          s += __shfl_xor(s, 4); s += __shfl_xor(s, 8);
          inv[rt2][reg] = 1.0f / s;
        }
      }
      // write P (unnormalized) to per-wave LDS
      #pragma unroll
      for (int rt2 = 0; rt2 < 2; rt2++)
        #pragma unroll
        for (int ct = 0; ct < 4; ct++)
          #pragma unroll
          for (int reg = 0; reg < 4; reg++) {
            int q = (hf * 2 + rt2) * 16 + (sub << 2) + reg;
            int k = ct * 16 + l15;
            unsigned byte = (unsigned)(q * 128 + k * 2) ^ (unsigned)((q & 7) << 4);
            *(unsigned short*)(Pb + byte) = f2bf(sc[rt2][ct][reg]);
          }
      // O = P V for this q-half
      f32x4 oa[2][2] = {{zf, zf}, {zf, zf}};
      #pragma unroll
      for (int kc = 0; kc < 2; kc++) {
        short8 pa[2];
        #pragma unroll
        for (int rt2 = 0; rt2 < 2; rt2++) {
          int q = (hf * 2 + rt2) * 16 + l15;
          unsigned byte = (unsigned)(q * 128 + kc * 64 + (sub << 4)) ^ (unsigned)((q & 7) << 4);
          pa[rt2] = *(const short8*)(Pb + byte);
        }
        #pragma unroll
        for (int dt = 0; dt < 2; dt++) {
          short8 b = *(const short8*)(vw + (size_t)(h * DH_ + dt * 16 + l15) * 64 + kc * 32 + sub * 8);
          #pragma unroll
          for (int rt2 = 0; rt2 < 2; rt2++)
            oa[rt2][dt] = __builtin_amdgcn_mfma_f32_16x16x32_bf16(pa[rt2], b, oa[rt2][dt], 0, 0, 0);
        }
      }
      // store o1 rows (normalize by inv)
      #pragma unroll
      for (int rt2 = 0; rt2 < 2; rt2++)
        #pragma unroll
        for (int dt = 0; dt < 2; dt++)
          #pragma unroll
          for (int reg = 0; reg < 4; reg++) {
            int q = (hf * 2 + rt2) * 16 + (sub << 2) + reg;
            ow[(size_t)q * C_ + h * DH_ + dt * 16 + l15] =
                f2bf(oa[rt2][dt][reg] * inv[rt2][reg]);
          }
    }
  }
}

// ------------------------------------------------------------------
// final: out = o1 @ Wf^T + bf, window-merged to (B,T,C,H,W)
// ------------------------------------------------------------------
__global__ __launch_bounds__(256) void final_gemm(
    const unsigned short* __restrict__ o1, const unsigned short* __restrict__ wf,
    const float* __restrict__ bfv, float* __restrict__ out, int winBase)
{
  __shared__ char smem[32768];
  char* As = smem;
  char* Bs = smem + 16384;

  const int blk = blockIdx.x;
  const int nt = blk % 3, mt = blk / 3;
  const int mbase = mt * 128, nbase = nt * 128;
  const int tid = threadIdx.x;
  const int w = tid >> 6, l = tid & 63;
  const int l15 = l & 15, sub = l >> 4;
  const int wm = w >> 1, wn = w & 1;
  const f32x4 zf = {0.f, 0.f, 0.f, 0.f};

  f32x4 acc[4][4];
  #pragma unroll
  for (int r = 0; r < 4; r++)
    #pragma unroll
    for (int c = 0; c < 4; c++) acc[r][c] = zf;

  for (int kb = 0; kb < C_; kb += 64) {
    __syncthreads();
    #pragma unroll
    for (int it = 0; it < 4; it++) {
      int row = it * 32 + (tid >> 3);
      int seg = tid & 7;
      unsigned byte = (unsigned)(row * 128 + seg * 16) ^ (unsigned)((row & 7) << 4);
      short8 va = *(const short8*)(o1 + (size_t)(mbase + row) * C_ + kb + seg * 8);
      *(short8*)(As + byte) = va;
      short8 vb = *(const short8*)(wf + (size_t)(nbase + row) * C_ + kb + seg * 8);
      *(short8*)(Bs + byte) = vb;
    }
    __syncthreads();
    #pragma unroll
    for (int kc = 0; kc < 2; kc++) {
      short8 a[4], b[4];
      #pragma unroll
      for (int r = 0; r < 4; r++) {
        int row = wm * 64 + r * 16 + l15;
        unsigned byte = (unsigned)(row * 128 + kc * 64 + (sub << 4)) ^ (unsigned)((row & 7) << 4);
        a[r] = *(const short8*)(As + byte);
      }
      #pragma unroll
      for (int c = 0; c < 4; c++) {
        int row = wn * 64 + c * 16 + l15;
        unsigned byte = (unsigned)(row * 128 + kc * 64 + (sub << 4)) ^ (unsigned)((row & 7) << 4);
        b[c] = *(const short8*)(Bs + byte);
      }
      #pragma unroll
      for (int r = 0; r < 4; r++)
        #pragma unroll
        for (int c = 0; c < 4; c++)
          acc[r][c] = __builtin_amdgcn_mfma_f32_16x16x32_bf16(a[r], b[c], acc[r][c], 0, 0, 0);
    }
  }

  #pragma unroll
  for (int r = 0; r < 4; r++) {
    int t0 = mbase + wm * 64 + r * 16 + (sub << 2);
    int win = winBase + (t0 >> 6), s0 = t0 & 63;
    int bt = win >> 8, wh = (win >> 4) & 15, ww = win & 15;
    int ii = s0 >> 3, jj = s0 & 7;
    #pragma unroll
    for (int c4 = 0; c4 < 4; c4++) {
      int c = nbase + wn * 64 + c4 * 16 + l15;
      float bias = bfv[c];
      f32x4 v;
      v[0] = acc[r][c4][0] + bias;
      v[1] = acc[r][c4][1] + bias;
      v[2] = acc[r][c4][2] + bias;
      v[3] = acc[r][c4][3] + bias;
      size_t off = (((size_t)bt * C_ + c) * HPX + wh * 8 + ii) * WPX + ww * 8 + jj;
      *(f32x4*)(out + off) = v;
    }
  }
}

// ------------------------------------------------------------------
extern "C" void kernel_launch(void* const* d_in, const int* in_sizes, int n_in,
                              void* d_out, int out_size, void* d_ws, size_t ws_size,
                              hipStream_t stream)
{
  (void)in_sizes; (void)n_in; (void)out_size;
  const float* x     = (const float*)d_in[0];
  const float* gamma = (const float*)d_in[1];
  const float* beta  = (const float*)d_in[2];
  const float* in_w  = (const float*)d_in[3];
  const float* in_b  = (const float*)d_in[4];
  const float* op_w  = (const float*)d_in[5];
  const float* op_b  = (const float*)d_in[6];
  const float* p_w   = (const float*)d_in[7];
  const float* p_b   = (const float*)d_in[8];
  float* out = (float*)d_out;
  char* ws = (char*)d_ws;

  const size_t XN_B   = (size_t)TOK_ * C_ * 2;        // 201,326,592 (xn, aliased by o1)
  const size_t QKV_B  = (size_t)TOK_ * 3 * C_ * 2;    // 603,979,776 full
  const size_t WQKV_B = (size_t)3 * C_ * C_ * 2;      // 884,736
  const size_t WF_B   = (size_t)C_ * C_ * 2;          // 294,912
  const size_t BF_B   = 2048;

  // adaptive chunking: pick fewest chunks whose qkv slab fits ws_size
  const int cand[9] = {1, 2, 4, 8, 16, 32, 64, 128, 256};
  int nchunks = 256;
  for (int i = 0; i < 9; i++) {
    size_t need = XN_B + QKV_B / (size_t)cand[i] + WQKV_B + WF_B + BF_B;
    if (need <= ws_size) { nchunks = cand[i]; break; }
  }
  const int chunkWins = NWIN_ / nchunks;
  const size_t chunkTok = (size_t)chunkWins * 64;
  const size_t qkv_slab = QKV_B / (size_t)nchunks;

  unsigned short* xn   = (unsigned short*)ws;                        // aliased by o1
  char* qbase          = ws + XN_B;
  unsigned short* wqkv = (unsigned short*)(ws + XN_B + qkv_slab);
  unsigned short* wf   = (unsigned short*)(ws + XN_B + qkv_slab + WQKV_B);
  float*          bfv  = (float*)(ws + XN_B + qkv_slab + WQKV_B + WF_B);

  unsigned short* qs  = (unsigned short*)qbase;
  unsigned short* ksp = qs + chunkTok * C_;
  unsigned short* vt  = ksp + chunkTok * C_;

  prep_kernel<<<1024, 256, 0, stream>>>(in_w, op_w, op_b, p_w, p_b, wqkv, wf, bfv);
  ln_win<<<NWIN_, 256, 0, stream>>>(x, gamma, beta, xn);

  const int mtiles = (int)(chunkTok / 128);
  for (int c = 0; c < nchunks; c++) {
    const int winBase = c * chunkWins;
    unsigned short* xn_c = xn + (size_t)winBase * 64 * C_;   // doubles as o1 region
    qkv_gemm<<<mtiles * 9, 256, 0, stream>>>(xn_c, wqkv, in_b, qs, ksp, vt);
    attn_win<<<chunkWins, 256, 0, stream>>>(qs, ksp, vt, xn_c);
    final_gemm<<<mtiles * 3, 256, 0, stream>>>(xn_c, wf, bfv, out, winBase);
  }
}